// Round 11
// baseline (156.866 us; speedup 1.0000x reference)
//
#include <hip/hip_runtime.h>
#include <hip/hip_bf16.h>
#include <stdint.h>

// ---------- types ----------
using frag8 = __attribute__((ext_vector_type(8))) short;   // 8 bf16 (4 VGPRs)
using f32x4 = __attribute__((ext_vector_type(4))) float;   // 4 fp32 acc

#define MFMA16 __builtin_amdgcn_mfma_f32_16x16x32_bf16

#if __has_builtin(__builtin_amdgcn_exp2f)
#define EXP2F(x) __builtin_amdgcn_exp2f(x)
#else
#define EXP2F(x) __expf((x) * 0.6931471805599453f)
#endif
#if __has_builtin(__builtin_amdgcn_rcpf)
#define RCPF(x) __builtin_amdgcn_rcpf(x)
#else
#define RCPF(x) (1.0f / (x))
#endif

// S' = (q.k)/8 * log2(e): folded into Q projection output
#define SCALE_Q 0.18033688011112042f

__device__ __forceinline__ short f2bf(float f) {
    union { __hip_bfloat16 h; short s; } c;
    c.h = __float2bfloat16(f);               // HW cvt
    return c.s;
}
__device__ __forceinline__ float bf2f(short s) {
    union { uint32_t u; float f; } x; x.u = ((uint32_t)(uint16_t)s) << 16;
    return x.f;
}
__device__ __forceinline__ uint32_t pack2bf(float a, float b) {
    float2 t; t.x = a; t.y = b;
    __hip_bfloat162 h = __float22bfloat162_rn(t);   // HW v_cvt_pk_bf16_f32
    union { __hip_bfloat162 h; uint32_t u; } c; c.h = h;
    return c.u;
}
__device__ __forceinline__ uint32_t addpk3(uint32_t a, uint32_t b, uint32_t c) {
    float a0 = bf2f((short)(a & 0xffff)), a1 = bf2f((short)(a >> 16));
    float b0 = bf2f((short)(b & 0xffff)), b1 = bf2f((short)(b >> 16));
    float c0 = bf2f((short)(c & 0xffff)), c1 = bf2f((short)(c >> 16));
    return pack2bf(a0 + b0 + c0, a1 + b1 + c1);
}

// ---------- K_compact: compaction + inverse permutation ----------
__global__ __launch_bounds__(64) void k_compact(const int* __restrict__ mask,
                                                int* __restrict__ idx,
                                                int* __restrict__ invp,
                                                int* __restrict__ nU) {
    const int b = blockIdx.x, ln = threadIdx.x;
    const int* m = mask + b * 2048;
    int tot = 0;
    for (int c = 0; c < 32; c++)
        tot += __popcll(__ballot(m[c * 64 + ln] != 0));
    int base = 0, mbase = tot;
    for (int c = 0; c < 32; c++) {
        int i = c * 64 + ln;
        int mv = m[i];
        unsigned long long bal = __ballot(mv != 0);
        int rank = __popcll(bal & ((1ull << ln) - 1ull));
        int nb = __popcll(bal);
        int pos = mv ? (base + rank) : (mbase + ln - rank);
        invp[b * 2048 + i] = pos;
        if (mv) idx[b * 2048 + pos] = i;
        base += nb; mbase += 64 - nb;
    }
    if (ln == 0) nU[b] = tot;
}

// ---------- K_psum3m: p0 += p1 + p2, then masked-row output fill ----------
__global__ __launch_bounds__(256) void k_psum3m(short* __restrict__ p0,
                                                const short* __restrict__ p1,
                                                const short* __restrict__ p2,
                                                const int* __restrict__ mask,
                                                const float* __restrict__ bO,
                                                const float* __restrict__ Qf,
                                                float* __restrict__ out) {
    const int n16 = 524288;                              // uint4 count (8MB bf16)
    int i0 = blockIdx.x * 256 + threadIdx.x;
    int st = gridDim.x * 256;
    for (int i = i0; i < n16; i += st) {
        uint4 a = ((const uint4*)p0)[i];
        uint4 b = ((const uint4*)p1)[i];
        uint4 c = ((const uint4*)p2)[i];
        uint4 r;
        r.x = addpk3(a.x, b.x, c.x); r.y = addpk3(a.y, b.y, c.y);
        r.z = addpk3(a.z, b.z, c.z); r.w = addpk3(a.w, b.w, c.w);
        ((uint4*)p0)[i] = r;
    }
    const int total = 4096 * 256;                        // float4 count of out
    for (int i = i0; i < total; i += st) {
        int row = i >> 8, c4 = i & 255;
        if (mask[row] == 0) {
            float4 q = ((const float4*)Qf)[i];
            float4 bv = ((const float4*)bO)[c4];
            float4 o; o.x = q.x + bv.x; o.y = q.y + bv.y;
            o.z = q.z + bv.z; o.w = q.w + bv.w;
            ((float4*)out)[i] = o;
        }
    }
}

// ---------- fused fp32 -> bf16 convert (7 segments; Q rows permuted) ----------
__global__ __launch_bounds__(256) void k_cvt_all(
    const float* __restrict__ s0, const float* __restrict__ s1,
    const float* __restrict__ s2, const float* __restrict__ s3,
    const float* __restrict__ s4, const float* __restrict__ s5,
    const float* __restrict__ s6, const int* __restrict__ invp,
    short* __restrict__ d0, short* __restrict__ d1, short* __restrict__ d2,
    short* __restrict__ d3, short* __restrict__ d4, short* __restrict__ d5,
    short* __restrict__ d6) {
    const int A4 = 1048576, W4 = 262144;       // float4 counts
    int i = blockIdx.x * 256 + threadIdx.x;
    int st = gridDim.x * 256;
    const int total = 3 * A4 + 4 * W4;
    for (; i < total; i += st) {
        const float* s; short* d; int j;
        bool permQ = false;
        if (i < A4)            { s = s0; d = d0; j = i; permQ = true; }
        else if (i < 2 * A4)   { s = s1; d = d1; j = i - A4; }
        else if (i < 3 * A4)   { s = s2; d = d2; j = i - 2 * A4; }
        else {
            int t = i - 3 * A4; int seg = t / W4; j = t - seg * W4;
            s = seg == 0 ? s3 : seg == 1 ? s4 : seg == 2 ? s5 : s6;
            d = seg == 0 ? d3 : seg == 1 ? d4 : seg == 2 ? d5 : d6;
        }
        float4 v = reinterpret_cast<const float4*>(s)[j];
        uint2 o;
        o.x = pack2bf(v.x, v.y);
        o.y = pack2bf(v.z, v.w);
        int jd = j;
        if (permQ) {
            int row = j >> 8, c4 = j & 255;
            int nrow = (row & ~2047) + invp[row];       // compacted row, same batch
            jd = (nrow << 8) + c4;
        }
        reinterpret_cast<uint2*>(d)[jd] = o;
    }
}

// ---------- swizzled staging: [64 rows][128B], XOR chunk ^= row&7 ----------
__device__ __forceinline__ void stage64x128(const short* __restrict__ g, int rs,
                                            short* lds, int tid) {
#pragma unroll
    for (int j = 0; j < 2; j++) {
        int chunk = j * 256 + tid;            // 0..511
        int row = chunk >> 3, c = chunk & 7;
        int sc = c ^ (row & 7);
        __builtin_amdgcn_global_load_lds(
            (const __attribute__((address_space(1))) uint32_t*)(g + (size_t)row * rs + sc * 8),
            (__attribute__((address_space(3))) uint32_t*)(lds + (j * 256 + (tid & 192)) * 8),
            16, 0, 0);
    }
}
// swizzled b128 read: logical (row, 16B-chunk cc)
__device__ __forceinline__ frag8 ldswz(const short* lds, int row, int cc) {
    return *(const frag8*)(lds + row * 64 + ((cc ^ (row & 7)) << 3));
}

// ---------- GEMM tile staging: [128 rows][32 cols] packed as 64 paired-rows ----------
__device__ __forceinline__ void stage_gswz(const short* __restrict__ g,
                                           short* lds, int tid) {
#pragma unroll
    for (int j = 0; j < 2; j++) {
        int c = j * 256 + tid;                // 0..511
        int lrow = c >> 3;
        int sc = (c & 7) ^ (lrow & 7);
        int grow = lrow * 2 + (sc >> 2);
        int gcol = (sc & 3) * 8;
        __builtin_amdgcn_global_load_lds(
            (const __attribute__((address_space(1))) uint32_t*)(g + (size_t)grow * 1024 + gcol),
            (__attribute__((address_space(3))) uint32_t*)(lds + (j * 256 + (tid & 192)) * 8),
            16, 0, 0);
    }
}
// 64-row variant: [64 rows][32 cols], 256 chunks, one per thread
__device__ __forceinline__ void stage_gswz64(const short* __restrict__ g,
                                             short* lds, int tid) {
    int c = tid;                              // 0..255
    int lrow = c >> 3;
    int sc = (c & 7) ^ (lrow & 7);
    int grow = lrow * 2 + (sc >> 2);
    int gcol = (sc & 3) * 8;
    __builtin_amdgcn_global_load_lds(
        (const __attribute__((address_space(1))) uint32_t*)(g + (size_t)grow * 1024 + gcol),
        (__attribute__((address_space(3))) uint32_t*)(lds + (tid & 192) * 8),
        16, 0, 0);
}
__device__ __forceinline__ frag8 ldgswz(const short* lds, int row, int cc) {
    int lrow = row >> 1;
    int s = (((row & 1) << 2) + cc) ^ (lrow & 7);
    return *(const frag8*)(lds + lrow * 64 + s * 8);
}

// ---------- K1: fused QKV projection ----------
// grid flat 768; wg%8 == tm low bits (XCD A-reuse).
// z==0 (Q): A rows are pre-compacted; tiles beyond ceil(n/128) skipped.
__global__ __launch_bounds__(256) void k_proj3(
    const short* __restrict__ A0, const short* __restrict__ A1, const short* __restrict__ A2,
    const short* __restrict__ B0, const short* __restrict__ B1, const short* __restrict__ B2,
    const float* __restrict__ bias0, const float* __restrict__ bias1, const float* __restrict__ bias2,
    const int* __restrict__ nU,
    short* __restrict__ dst0, short* __restrict__ dst1, short* __restrict__ dst2) {
    __shared__ short lA[2][4096];
    __shared__ short lB[2][4096];
    const int wg = blockIdx.x;
    const int tmlow = wg & 7, tnb = (wg >> 3) & 7, rest = wg >> 6;
    const int tmh = rest & 3, z = rest >> 2;    // z 0..2
    const int tmb = tmlow | (tmh << 3);         // 0..31
    if (z == 0 && (tmb & 15) * 128 >= nU[tmb >> 4]) return;  // dead Q tile
    const short* A  = z == 0 ? A0 : z == 1 ? A1 : A2;
    const short* Bt = z == 0 ? B0 : z == 1 ? B1 : B2;
    const float* bias = z == 0 ? bias0 : z == 1 ? bias1 : bias2;
    short* dst = z == 0 ? dst0 : z == 1 ? dst1 : dst2;
    const float scale = z == 0 ? SCALE_Q : 1.0f;

    const int tid = threadIdx.x, w = tid >> 6, ln = tid & 63;
    const int wm = w >> 1, wn = w & 1, r16 = ln & 15, g = ln >> 4;
    const int tn = tnb * 128, tm = tmb * 128;
    const short* Ab = A + (size_t)tm * 1024;
    const short* Bb = Bt + (size_t)tn * 1024;

    f32x4 acc[4][4] = {};
    stage_gswz(Ab, &lA[0][0], tid);
    stage_gswz(Bb, &lB[0][0], tid);
    int buf = 0;
    for (int ks = 0; ks < 32; ks++) {
        __syncthreads();
        if (ks + 1 < 32) {
            stage_gswz(Ab + (ks + 1) * 32, &lA[buf ^ 1][0], tid);
            stage_gswz(Bb + (ks + 1) * 32, &lB[buf ^ 1][0], tid);
        }
        frag8 af[4], bg[4];
#pragma unroll
        for (int mf = 0; mf < 4; mf++)
            af[mf] = ldgswz(&lA[buf][0], wm * 64 + mf * 16 + r16, g);
#pragma unroll
        for (int nf = 0; nf < 4; nf++)
            bg[nf] = ldgswz(&lB[buf][0], wn * 64 + nf * 16 + r16, g);
#pragma unroll
        for (int mf = 0; mf < 4; mf++)
#pragma unroll
            for (int nf = 0; nf < 4; nf++)
                acc[mf][nf] = MFMA16(af[mf], bg[nf], acc[mf][nf], 0, 0, 0);
        buf ^= 1;
    }
#pragma unroll
    for (int mf = 0; mf < 4; mf++)
#pragma unroll
        for (int r = 0; r < 4; r++) {
            int m = tm + wm * 64 + mf * 16 + g * 4 + r;
            int b = m >> 11, seq = m & 2047;
#pragma unroll
            for (int nf = 0; nf < 4; nf++) {
                int n = tn + wn * 64 + nf * 16 + r16;
                float val = (acc[mf][nf][r] + bias[n]) * scale;
                int h = n >> 6, d = n & 63;
                dst[((size_t)(b * 16 + h) * 2048 + seq) * 64 + d] = f2bf(val);
            }
        }
}

// ---------- K2: stats + fused v-scale; wave owns 32 k (128 k / block) ----------
__global__ __launch_bounds__(256, 3) void k_stats(const short* __restrict__ k_s,
                                                  const short* __restrict__ q_s,
                                                  const int* __restrict__ nU,
                                                  const short* __restrict__ v_s,
                                                  short* __restrict__ vhatT) {
    __shared__ short lQ[2][4096];
    __shared__ float lD[128];
    __shared__ short lT[128 * 70];              // v tile [k][d], row stride 70
    const int wg = blockIdx.x;                  // 512 blocks
    const int x = wg & 7, r2 = wg >> 3;
    const int kt = r2 & 15;                     // 16 kt tiles of 128 k
    const int bh = x + 8 * (r2 >> 4);           // bh-grouped per XCD
    const int b = bh >> 4;
    const int n = nU[b], nUr = (n + 63) & ~63;
    const int tid = threadIdx.x, w = tid >> 6, ln = tid & 63;
    const int r16 = ln & 15, g = ln >> 4;
    const int kbase = kt * 128 + w * 32;

    const short* kp = k_s + ((size_t)bh * 2048 + kbase) * 64;
    frag8 kf[2][2];
#pragma unroll
    for (int mfk = 0; mfk < 2; mfk++)
#pragma unroll
        for (int kk = 0; kk < 2; kk++)
            kf[mfk][kk] = *(const frag8*)(kp + (mfk * 16 + r16) * 64 + kk * 32 + g * 8);

    const short* qsp = q_s + (size_t)bh * 2048 * 64;
    float dacc[2][4] = {};
    const f32x4 z4 = {0.f, 0.f, 0.f, 0.f};

    if (nUr > 0) {
        stage64x128(qsp, 64, &lQ[0][0], tid);
        int buf = 0;
        for (int qb = 0; qb < nUr; qb += 64) {
            __syncthreads();
            if (qb + 64 < nUr)
                stage64x128(qsp + (size_t)(qb + 64) * 64, 64, &lQ[buf ^ 1][0], tid);
            const short* Qc = &lQ[buf][0];
#pragma unroll
            for (int nf = 0; nf < 4; nf++) {
                float fm = (qb + nf * 16 + r16 < n) ? 1.0f : 0.0f;
                frag8 bq0 = ldswz(Qc, nf * 16 + r16, g);
                frag8 bq1 = ldswz(Qc, nf * 16 + r16, 4 + g);
#pragma unroll
                for (int mfk = 0; mfk < 2; mfk++) {
                    f32x4 s = MFMA16(kf[mfk][0], bq0, z4, 0, 0, 0);
                    s = MFMA16(kf[mfk][1], bq1, s, 0, 0, 0);
#pragma unroll
                    for (int r = 0; r < 4; r++)
                        dacc[mfk][r] += fm * EXP2F(s[r]);
                }
            }
            buf ^= 1;
        }
    }
#pragma unroll
    for (int mfk = 0; mfk < 2; mfk++)
#pragma unroll
        for (int r = 0; r < 4; r++) {
            float v = dacc[mfk][r];
#pragma unroll
            for (int off = 1; off < 16; off <<= 1)
                v += __shfl_xor(v, off, 16);
            dacc[mfk][r] = v;
        }
    if (r16 == 0) {
#pragma unroll
        for (int mfk = 0; mfk < 2; mfk++)
#pragma unroll
            for (int r = 0; r < 4; r++)
                lD[w * 32 + mfk * 16 + g * 4 + r] = RCPF(dacc[mfk][r]);
    }
    // stage v tile [128 k][64 d] into lT (stride 70)
    const short* vrow = v_s + ((size_t)bh * 2048 + kt * 128) * 64;
#pragma unroll
    for (int i = 0; i < 8; i++) {
        int idx4 = i * 256 + tid;               // 4-short units, 0..2047
        int row = idx4 >> 4, c4 = idx4 & 15;
        uint2 u = *(const uint2*)(vrow + (size_t)row * 64 + c4 * 4);
        *(uint32_t*)&lT[row * 70 + c4 * 4]     = u.x;
        *(uint32_t*)&lT[row * 70 + c4 * 4 + 2] = u.y;
    }
    __syncthreads();
    // transposed write: vhatT[bh][d][kt*128 + kc*32 .. +32]
    {
        int d = tid >> 2, kc = tid & 3;
        short* dstp = vhatT + ((size_t)bh * 64 + d) * 2048 + kt * 128 + kc * 32;
        uint32_t wd[16];
#pragma unroll
        for (int j2 = 0; j2 < 16; j2++) {
            int k0 = kc * 32 + j2 * 2;
            float v0 = bf2f(lT[k0 * 70 + d]) * lD[k0];
            float v1 = bf2f(lT[(k0 + 1) * 70 + d]) * lD[k0 + 1];
            wd[j2] = pack2bf(v0, v1);
        }
#pragma unroll
        for (int j4 = 0; j4 < 4; j4++) {
            uint4 o = {wd[j4 * 4], wd[j4 * 4 + 1], wd[j4 * 4 + 2], wd[j4 * 4 + 3]};
            *((uint4*)dstp + j4) = o;
        }
    }
}

// ---------- K4: apply; wave owns 32 q (128 q / block), SPLIT-3 over k ----------
// Output rows stay COMPACTED; scatter deferred to k_final.
__global__ __launch_bounds__(256, 3) void k_apply(const short* __restrict__ q_s,
                                                  const short* __restrict__ k_s,
                                                  const short* __restrict__ vhatT,
                                                  const int* __restrict__ nU,
                                                  short* __restrict__ p0,
                                                  short* __restrict__ p1,
                                                  short* __restrict__ p2) {
    __shared__ short lK[2][4096];
    __shared__ short lV[2][4096];
    __shared__ short lP[128 * 64];              // P[q][k] bf16, chunk-XOR swizzled
    const int wg = blockIdx.x;                  // 1536 blocks
    const int x = wg & 7, qt = (wg >> 3) & 15, y = wg >> 7;  // y 0..11
    const int bhsp = y * 8 + x;                 // 0..95; qt-blocks share XCD
    const int bh = bhsp / 3, sp = bhsp - bh * 3;
    const int b = bh >> 4, h = bh & 15;
    const int n = nU[b];
    if (qt * 128 >= n) return;                  // uniform early exit
    const int kc0 = sp * 11, nch = (sp == 2) ? 10 : 11;   // 11+11+10 = 32 chunks
    const int tid = threadIdx.x, w = tid >> 6, ln = tid & 63;
    const int r16 = ln & 15, g = ln >> 4;

    const short* qp = q_s + ((size_t)bh * 2048 + qt * 128 + w * 32) * 64;
    frag8 qf[2][2];
#pragma unroll
    for (int qi = 0; qi < 2; qi++)
#pragma unroll
        for (int kk = 0; kk < 2; kk++)
            qf[qi][kk] = *(const frag8*)(qp + (qi * 16 + r16) * 64 + kk * 32 + g * 8);

    const short* kp = k_s + ((size_t)bh * 2048 + kc0 * 64) * 64;
    const short* vp = vhatT + (size_t)bh * 64 * 2048 + kc0 * 64;

    f32x4 oacc[2][4] = {};
    const f32x4 z4 = {0.f, 0.f, 0.f, 0.f};

    stage64x128(kp, 64, &lK[0][0], tid);
    stage64x128(vp, 2048, &lV[0][0], tid);
    int buf = 0;
    for (int c = 0; c < nch; c++) {
        __syncthreads();
        if (c + 1 < nch) {
            stage64x128(kp + (size_t)(c + 1) * 64 * 64, 64, &lK[buf ^ 1][0], tid);
            stage64x128(vp + (c + 1) * 64, 2048, &lV[buf ^ 1][0], tid);
        }
        const short* Kc = &lK[buf][0];
        const short* Vc = &lV[buf][0];
        // hoist V fragment reads (independent of QK^T chain)
        frag8 vb[4][2];
#pragma unroll
        for (int nf = 0; nf < 4; nf++)
#pragma unroll
            for (int kk = 0; kk < 2; kk++)
                vb[nf][kk] = ldswz(Vc, nf * 16 + r16, kk * 4 + g);
        // S^T (64k x 32q per wave) -> exp2 -> P[q][k]
#pragma unroll
        for (int qi = 0; qi < 2; qi++) {
            const int prow = w * 32 + qi * 16 + r16;
            const int rx = prow & 7;
#pragma unroll
            for (int mf2 = 0; mf2 < 4; mf2++) {
                f32x4 s = z4;
#pragma unroll
                for (int kk = 0; kk < 2; kk++)
                    s = MFMA16(ldswz(Kc, mf2 * 16 + r16, kk * 4 + g), qf[qi][kk], s, 0, 0, 0);
                float e0 = EXP2F(s[0]), e1 = EXP2F(s[1]);
                float e2 = EXP2F(s[2]), e3 = EXP2F(s[3]);
                uint2 pk;
                pk.x = pack2bf(e0, e1);
                pk.y = pack2bf(e2, e3);
                int o = mf2 * 32 + g * 8;       // byte offset in 128B P row
                int addr = prow * 128 + (((o >> 4) ^ rx) << 4) + (o & 15);
                *(uint2*)((char*)lP + addr) = pk;
            }
        }
        // PV: oacc[qi][d] += P[q][k] * vhat[d][k]  (same-wave P RAW: DS in-order)
#pragma unroll
        for (int qi = 0; qi < 2; qi++) {
            const int prow = w * 32 + qi * 16 + r16;
            const int rx = prow & 7;
            frag8 pa[2];
#pragma unroll
            for (int kk = 0; kk < 2; kk++)
                pa[kk] = *(const frag8*)((char*)lP + prow * 128 + (((kk * 4 + g) ^ rx) << 4));
#pragma unroll
            for (int nf = 0; nf < 4; nf++)
#pragma unroll
                for (int kk = 0; kk < 2; kk++)
                    oacc[qi][nf] = MFMA16(pa[kk], vb[nf][kk], oacc[qi][nf], 0, 0, 0);
        }
        buf ^= 1;
    }
    // epilogue: store compacted rows (coalesced); rows >= n guarded
    short* op = sp == 0 ? p0 : sp == 1 ? p1 : p2;
#pragma unroll
    for (int qi = 0; qi < 2; qi++)
#pragma unroll
        for (int r = 0; r < 4; r++) {
            int lq = qt * 128 + w * 32 + qi * 16 + g * 4 + r;
            if (lq < n) {
#pragma unroll
                for (int nf = 0; nf < 4; nf++) {
                    int d = nf * 16 + r16;
                    op[((size_t)(b * 2048 + lq)) * 1024 + h * 64 + d] = f2bf(oacc[qi][nf][r]);
                }
            }
        }
}

// ---------- K5: out = attn_c @ Wo^T + b_O + Q, scatter rows via idx ----------
// 128x64 tiles, grid 512; wg%8 groups tn-blocks of a tm per XCD; dead tiles skipped.
__global__ __launch_bounds__(256) void k_final(const short* __restrict__ A,
                                               const short* __restrict__ Bt,
                                               const float* __restrict__ bias,
                                               const float* __restrict__ Qres,
                                               const int* __restrict__ idx,
                                               const int* __restrict__ nU,
                                               float* __restrict__ out) {
    __shared__ short lA[2][4096];
    __shared__ short lB[2][2048];
    const int wg = blockIdx.x;                 // 512 blocks
    const int x = wg & 7, r2 = wg >> 3;
    const int tnb = r2 & 15, tmh = r2 >> 4;    // tnb 0..15, tmh 0..3
    const int tmb = x | (tmh << 3);            // 0..31
    const int bb = tmb >> 4;
    const int n = nU[bb];
    if ((tmb & 15) * 128 >= n) return;         // dead (masked) tile
    const int tid = threadIdx.x, w = tid >> 6, ln = tid & 63;
    const int wm = w >> 1, wn = w & 1, r16 = ln & 15, g = ln >> 4;
    const int tn = tnb * 64, tm = tmb * 128;
    const short* Ab = A + (size_t)tm * 1024;
    const short* Bb = Bt + (size_t)tn * 1024;

    f32x4 acc[4][2] = {};
    stage_gswz(Ab, &lA[0][0], tid);
    stage_gswz64(Bb, &lB[0][0], tid);
    int buf = 0;
    for (int ks = 0; ks < 32; ks++) {
        __syncthreads();
        if (ks + 1 < 32) {
            stage_gswz(Ab + (ks + 1) * 32, &lA[buf ^ 1][0], tid);
            stage_gswz64(Bb + (ks + 1) * 32, &lB[buf ^ 1][0], tid);
        }
        frag8 af[4], bg[2];
#pragma unroll
        for (int mf = 0; mf < 4; mf++)
            af[mf] = ldgswz(&lA[buf][0], wm * 64 + mf * 16 + r16, g);
#pragma unroll
        for (int nf = 0; nf < 2; nf++)
            bg[nf] = ldgswz(&lB[buf][0], wn * 32 + nf * 16 + r16, g);
#pragma unroll
        for (int mf = 0; mf < 4; mf++)
#pragma unroll
            for (int nf = 0; nf < 2; nf++)
                acc[mf][nf] = MFMA16(af[mf], bg[nf], acc[mf][nf], 0, 0, 0);
        buf ^= 1;
    }
#pragma unroll
    for (int mf = 0; mf < 4; mf++)
#pragma unroll
        for (int r = 0; r < 4; r++) {
            int m = tm + wm * 64 + mf * 16 + g * 4 + r;
            int i = m & 2047;
            if (i < n) {
                int qg = idx[bb * 2048 + i];
                size_t rowo = ((size_t)(bb * 2048 + qg)) * 1024;
#pragma unroll
                for (int nf = 0; nf < 2; nf++) {
                    int nn = tn + wn * 32 + nf * 16 + r16;
                    float val = acc[mf][nf][r] + bias[nn] + Qres[rowo + nn];
                    out[rowo + nn] = val;
                }
            }
        }
}

// ---------- launch ----------
extern "C" void kernel_launch(void* const* d_in, const int* in_sizes, int n_in,
                              void* d_out, int out_size, void* d_ws, size_t ws_size,
                              hipStream_t stream) {
    (void)in_sizes; (void)n_in; (void)out_size; (void)ws_size;
    const float* Qf  = (const float*)d_in[0];
    const float* Kf  = (const float*)d_in[1];
    const float* Vf  = (const float*)d_in[2];
    const int*   msk = (const int*)d_in[3];
    const float* WQ  = (const float*)d_in[4];
    const float* bQ  = (const float*)d_in[5];
    const float* WK  = (const float*)d_in[6];
    const float* bK  = (const float*)d_in[7];
    const float* WV  = (const float*)d_in[8];
    const float* bV  = (const float*)d_in[9];
    const float* WO  = (const float*)d_in[10];
    const float* bO  = (const float*)d_in[11];
    float* out = (float*)d_out;

    char* p = (char*)d_ws;
    const size_t SZ_ACT = (size_t)4096 * 1024 * 2;  // 8 MB bf16
    const size_t SZ_W   = (size_t)1024 * 1024 * 2;  // 2 MB
    short* Qb  = (short*)p; p += SZ_ACT;
    short* Kb  = (short*)p; p += SZ_ACT;
    short* Vb  = (short*)p; p += SZ_ACT;
    short* q_s = (short*)p; p += SZ_ACT;            // compacted q projections
    short* k_s = (short*)p; p += SZ_ACT;
    short* v_s = (short*)p; p += SZ_ACT;
    short* Wqb = (short*)p; p += SZ_W;
    short* Wkb = (short*)p; p += SZ_W;
    short* Wvb = (short*)p; p += SZ_W;
    short* Wob = (short*)p; p += SZ_W;
    int* idx  = (int*)p; p += (size_t)2 * 2048 * 4;
    int* invp = (int*)p; p += (size_t)2 * 2048 * 4;
    int* nU   = (int*)p; p += 256;
    short* vhatT = Qb;   // dead after proj3
    short* p0    = Kb;   // dead after proj3
    short* p1    = Vb;   // dead after proj3
    short* p2    = v_s;  // dead after k_stats

    // compaction (mask-only dependency)
    k_compact<<<2, 64, 0, stream>>>(msk, idx, invp, nU);

    // fused converts: activations + weights -> bf16 (Q rows permuted to compacted order)
    k_cvt_all<<<4096, 256, 0, stream>>>(Qf, Kf, Vf, WQ, WK, WV, WO, invp,
                                        Qb, Kb, Vb, Wqb, Wkb, Wvb, Wob);

    // fused projections (z: 0=Q scaled+compacted, 1=K, 2=V); XCD tm-swizzle
    k_proj3<<<768, 256, 0, stream>>>(Qb, Kb, Vb, Wqb, Wkb, Wvb,
                                     bQ, bK, bV, nU, q_s, k_s, v_s);

    // column softmax denominators + fused v-scale/transpose (128 k / block)
    k_stats<<<512, 256, 0, stream>>>(k_s, q_s, nU, v_s, vhatT);

    // attention apply, 32 q / wave, split-3 over k, compacted output
    k_apply<<<1536, 256, 0, stream>>>(q_s, k_s, vhatT, nU, p0, p1, p2);

    // sum partials into p0 + fill masked output rows (fused)
    k_psum3m<<<2048, 256, 0, stream>>>(p0, p1, p2, msk, bO, Qf, out);

    // output projection + bias + residual, scatter via idx (dead tiles skipped)
    k_final<<<512, 256, 0, stream>>>(p0, Wob, bO, Qf, idx, nU, out);
}

// Round 12
// 151.775 us; speedup vs baseline: 1.0335x; 1.0335x over previous
//
#include <hip/hip_runtime.h>
#include <hip/hip_bf16.h>
#include <stdint.h>

// ---------- types ----------
using frag8 = __attribute__((ext_vector_type(8))) short;   // 8 bf16 (4 VGPRs)
using f32x4 = __attribute__((ext_vector_type(4))) float;   // 4 fp32 acc

#define MFMA16 __builtin_amdgcn_mfma_f32_16x16x32_bf16

#if __has_builtin(__builtin_amdgcn_exp2f)
#define EXP2F(x) __builtin_amdgcn_exp2f(x)
#else
#define EXP2F(x) __expf((x) * 0.6931471805599453f)
#endif
#if __has_builtin(__builtin_amdgcn_rcpf)
#define RCPF(x) __builtin_amdgcn_rcpf(x)
#else
#define RCPF(x) (1.0f / (x))
#endif

// S' = (q.k)/8 * log2(e): folded into Q projection output
#define SCALE_Q 0.18033688011112042f

__device__ __forceinline__ short f2bf(float f) {
    union { __hip_bfloat16 h; short s; } c;
    c.h = __float2bfloat16(f);               // HW cvt
    return c.s;
}
__device__ __forceinline__ float bf2f(short s) {
    union { uint32_t u; float f; } x; x.u = ((uint32_t)(uint16_t)s) << 16;
    return x.f;
}
__device__ __forceinline__ uint32_t pack2bf(float a, float b) {
    float2 t; t.x = a; t.y = b;
    __hip_bfloat162 h = __float22bfloat162_rn(t);   // HW v_cvt_pk_bf16_f32
    union { __hip_bfloat162 h; uint32_t u; } c; c.h = h;
    return c.u;
}
__device__ __forceinline__ uint32_t addpk(uint32_t a, uint32_t b) {
    float a0 = bf2f((short)(a & 0xffff)), a1 = bf2f((short)(a >> 16));
    float b0 = bf2f((short)(b & 0xffff)), b1 = bf2f((short)(b >> 16));
    return pack2bf(a0 + b0, a1 + b1);
}

// ---------- K_compact: compaction + inverse permutation ----------
__global__ __launch_bounds__(64) void k_compact(const int* __restrict__ mask,
                                                int* __restrict__ idx,
                                                int* __restrict__ invp,
                                                int* __restrict__ nU) {
    const int b = blockIdx.x, ln = threadIdx.x;
    const int* m = mask + b * 2048;
    int tot = 0;
    for (int c = 0; c < 32; c++)
        tot += __popcll(__ballot(m[c * 64 + ln] != 0));
    int base = 0, mbase = tot;
    for (int c = 0; c < 32; c++) {
        int i = c * 64 + ln;
        int mv = m[i];
        unsigned long long bal = __ballot(mv != 0);
        int rank = __popcll(bal & ((1ull << ln) - 1ull));
        int nb = __popcll(bal);
        int pos = mv ? (base + rank) : (mbase + ln - rank);
        invp[b * 2048 + i] = pos;
        if (mv) idx[b * 2048 + pos] = i;
        base += nb; mbase += 64 - nb;
    }
    if (ln == 0) nU[b] = tot;
}

// ---------- K_psum2m: p0 += p1, then masked-row output fill (fused) ----------
__global__ __launch_bounds__(256) void k_psum2m(short* __restrict__ p0,
                                                const short* __restrict__ p1,
                                                const int* __restrict__ mask,
                                                const float* __restrict__ bO,
                                                const float* __restrict__ Qf,
                                                float* __restrict__ out) {
    const int n16 = 524288;                              // uint4 count (8MB bf16)
    int i0 = blockIdx.x * 256 + threadIdx.x;
    int st = gridDim.x * 256;
    for (int i = i0; i < n16; i += st) {
        uint4 a = ((const uint4*)p0)[i];
        uint4 b = ((const uint4*)p1)[i];
        uint4 r;
        r.x = addpk(a.x, b.x); r.y = addpk(a.y, b.y);
        r.z = addpk(a.z, b.z); r.w = addpk(a.w, b.w);
        ((uint4*)p0)[i] = r;
    }
    const int total = 4096 * 256;                        // float4 count of out
    for (int i = i0; i < total; i += st) {
        int row = i >> 8, c4 = i & 255;
        if (mask[row] == 0) {
            float4 q = ((const float4*)Qf)[i];
            float4 bv = ((const float4*)bO)[c4];
            float4 o; o.x = q.x + bv.x; o.y = q.y + bv.y;
            o.z = q.z + bv.z; o.w = q.w + bv.w;
            ((float4*)out)[i] = o;
        }
    }
}

// ---------- fused fp32 -> bf16 convert (7 segments; Q rows permuted) ----------
__global__ __launch_bounds__(256) void k_cvt_all(
    const float* __restrict__ s0, const float* __restrict__ s1,
    const float* __restrict__ s2, const float* __restrict__ s3,
    const float* __restrict__ s4, const float* __restrict__ s5,
    const float* __restrict__ s6, const int* __restrict__ invp,
    const int* __restrict__ nU,
    short* __restrict__ d0, short* __restrict__ d1, short* __restrict__ d2,
    short* __restrict__ d3, short* __restrict__ d4, short* __restrict__ d5,
    short* __restrict__ d6) {
    const int A4 = 1048576, W4 = 262144;       // float4 counts
    int i = blockIdx.x * 256 + threadIdx.x;
    int st = gridDim.x * 256;
    const int total = 3 * A4 + 4 * W4;
    for (; i < total; i += st) {
        const float* s; short* d; int j;
        bool permQ = false;
        if (i < A4)            { s = s0; d = d0; j = i; permQ = true; }
        else if (i < 2 * A4)   { s = s1; d = d1; j = i - A4; }
        else if (i < 3 * A4)   { s = s2; d = d2; j = i - 2 * A4; }
        else {
            int t = i - 3 * A4; int seg = t / W4; j = t - seg * W4;
            s = seg == 0 ? s3 : seg == 1 ? s4 : seg == 2 ? s5 : s6;
            d = seg == 0 ? d3 : seg == 1 ? d4 : seg == 2 ? d5 : d6;
        }
        int jd = j;
        if (permQ) {
            int row = j >> 8, c4 = j & 255;
            int pos = invp[row];
            if (pos >= nU[row >> 11]) continue;         // dead Q row: skip
            int nrow = (row & ~2047) + pos;             // compacted row, same batch
            jd = (nrow << 8) + c4;
        }
        float4 v = reinterpret_cast<const float4*>(s)[j];
        uint2 o;
        o.x = pack2bf(v.x, v.y);
        o.y = pack2bf(v.z, v.w);
        reinterpret_cast<uint2*>(d)[jd] = o;
    }
}

// ---------- swizzled staging: [64 rows][128B], XOR chunk ^= row&7 ----------
__device__ __forceinline__ void stage64x128(const short* __restrict__ g, int rs,
                                            short* lds, int tid) {
#pragma unroll
    for (int j = 0; j < 2; j++) {
        int chunk = j * 256 + tid;            // 0..511
        int row = chunk >> 3, c = chunk & 7;
        int sc = c ^ (row & 7);
        __builtin_amdgcn_global_load_lds(
            (const __attribute__((address_space(1))) uint32_t*)(g + (size_t)row * rs + sc * 8),
            (__attribute__((address_space(3))) uint32_t*)(lds + (j * 256 + (tid & 192)) * 8),
            16, 0, 0);
    }
}
// swizzled b128 read: logical (row, 16B-chunk cc)
__device__ __forceinline__ frag8 ldswz(const short* lds, int row, int cc) {
    return *(const frag8*)(lds + row * 64 + ((cc ^ (row & 7)) << 3));
}

// ---------- GEMM tile staging: [128 rows][32 cols] packed as 64 paired-rows ----------
__device__ __forceinline__ void stage_gswz(const short* __restrict__ g,
                                           short* lds, int tid) {
#pragma unroll
    for (int j = 0; j < 2; j++) {
        int c = j * 256 + tid;                // 0..511
        int lrow = c >> 3;
        int sc = (c & 7) ^ (lrow & 7);
        int grow = lrow * 2 + (sc >> 2);
        int gcol = (sc & 3) * 8;
        __builtin_amdgcn_global_load_lds(
            (const __attribute__((address_space(1))) uint32_t*)(g + (size_t)grow * 1024 + gcol),
            (__attribute__((address_space(3))) uint32_t*)(lds + (j * 256 + (tid & 192)) * 8),
            16, 0, 0);
    }
}
// 64-row variant: [64 rows][32 cols], 256 chunks, one per thread
__device__ __forceinline__ void stage_gswz64(const short* __restrict__ g,
                                             short* lds, int tid) {
    int c = tid;                              // 0..255
    int lrow = c >> 3;
    int sc = (c & 7) ^ (lrow & 7);
    int grow = lrow * 2 + (sc >> 2);
    int gcol = (sc & 3) * 8;
    __builtin_amdgcn_global_load_lds(
        (const __attribute__((address_space(1))) uint32_t*)(g + (size_t)grow * 1024 + gcol),
        (__attribute__((address_space(3))) uint32_t*)(lds + (tid & 192) * 8),
        16, 0, 0);
}
__device__ __forceinline__ frag8 ldgswz(const short* lds, int row, int cc) {
    int lrow = row >> 1;
    int s = (((row & 1) << 2) + cc) ^ (lrow & 7);
    return *(const frag8*)(lds + lrow * 64 + s * 8);
}

// ---------- K1: fused QKV projection ----------
// grid flat 768; wg%8 == tm low bits (XCD A-reuse).
// z==0 (Q): A rows are pre-compacted; tiles beyond ceil(n/128) skipped.
__global__ __launch_bounds__(256) void k_proj3(
    const short* __restrict__ A0, const short* __restrict__ A1, const short* __restrict__ A2,
    const short* __restrict__ B0, const short* __restrict__ B1, const short* __restrict__ B2,
    const float* __restrict__ bias0, const float* __restrict__ bias1, const float* __restrict__ bias2,
    const int* __restrict__ nU,
    short* __restrict__ dst0, short* __restrict__ dst1, short* __restrict__ dst2) {
    __shared__ short lA[2][4096];
    __shared__ short lB[2][4096];
    const int wg = blockIdx.x;
    const int tmlow = wg & 7, tnb = (wg >> 3) & 7, rest = wg >> 6;
    const int tmh = rest & 3, z = rest >> 2;    // z 0..2
    const int tmb = tmlow | (tmh << 3);         // 0..31
    if (z == 0 && (tmb & 15) * 128 >= nU[tmb >> 4]) return;  // dead Q tile
    const short* A  = z == 0 ? A0 : z == 1 ? A1 : A2;
    const short* Bt = z == 0 ? B0 : z == 1 ? B1 : B2;
    const float* bias = z == 0 ? bias0 : z == 1 ? bias1 : bias2;
    short* dst = z == 0 ? dst0 : z == 1 ? dst1 : dst2;
    const float scale = z == 0 ? SCALE_Q : 1.0f;

    const int tid = threadIdx.x, w = tid >> 6, ln = tid & 63;
    const int wm = w >> 1, wn = w & 1, r16 = ln & 15, g = ln >> 4;
    const int tn = tnb * 128, tm = tmb * 128;
    const short* Ab = A + (size_t)tm * 1024;
    const short* Bb = Bt + (size_t)tn * 1024;

    f32x4 acc[4][4] = {};
    stage_gswz(Ab, &lA[0][0], tid);
    stage_gswz(Bb, &lB[0][0], tid);
    int buf = 0;
    for (int ks = 0; ks < 32; ks++) {
        __syncthreads();
        if (ks + 1 < 32) {
            stage_gswz(Ab + (ks + 1) * 32, &lA[buf ^ 1][0], tid);
            stage_gswz(Bb + (ks + 1) * 32, &lB[buf ^ 1][0], tid);
        }
        frag8 af[4], bg[4];
#pragma unroll
        for (int mf = 0; mf < 4; mf++)
            af[mf] = ldgswz(&lA[buf][0], wm * 64 + mf * 16 + r16, g);
#pragma unroll
        for (int nf = 0; nf < 4; nf++)
            bg[nf] = ldgswz(&lB[buf][0], wn * 64 + nf * 16 + r16, g);
#pragma unroll
        for (int mf = 0; mf < 4; mf++)
#pragma unroll
            for (int nf = 0; nf < 4; nf++)
                acc[mf][nf] = MFMA16(af[mf], bg[nf], acc[mf][nf], 0, 0, 0);
        buf ^= 1;
    }
#pragma unroll
    for (int mf = 0; mf < 4; mf++)
#pragma unroll
        for (int r = 0; r < 4; r++) {
            int m = tm + wm * 64 + mf * 16 + g * 4 + r;
            int b = m >> 11, seq = m & 2047;
#pragma unroll
            for (int nf = 0; nf < 4; nf++) {
                int n = tn + wn * 64 + nf * 16 + r16;
                float val = (acc[mf][nf][r] + bias[n]) * scale;
                int h = n >> 6, d = n & 63;
                dst[((size_t)(b * 16 + h) * 2048 + seq) * 64 + d] = f2bf(val);
            }
        }
}

// ---------- K2: stats + fused v-scale; wave owns 32 k (128 k / block) ----------
__global__ __launch_bounds__(256, 3) void k_stats(const short* __restrict__ k_s,
                                                  const short* __restrict__ q_s,
                                                  const int* __restrict__ nU,
                                                  const short* __restrict__ v_s,
                                                  short* __restrict__ vhatT) {
    __shared__ short lQ[2][4096];
    __shared__ float lD[128];
    __shared__ short lT[128 * 70];              // v tile [k][d], row stride 70
    const int wg = blockIdx.x;                  // 512 blocks
    const int x = wg & 7, r2 = wg >> 3;
    const int kt = r2 & 15;                     // 16 kt tiles of 128 k
    const int bh = x + 8 * (r2 >> 4);           // bh-grouped per XCD
    const int b = bh >> 4;
    const int n = nU[b], nUr = (n + 63) & ~63;
    const int tid = threadIdx.x, w = tid >> 6, ln = tid & 63;
    const int r16 = ln & 15, g = ln >> 4;
    const int kbase = kt * 128 + w * 32;

    const short* kp = k_s + ((size_t)bh * 2048 + kbase) * 64;
    frag8 kf[2][2];
#pragma unroll
    for (int mfk = 0; mfk < 2; mfk++)
#pragma unroll
        for (int kk = 0; kk < 2; kk++)
            kf[mfk][kk] = *(const frag8*)(kp + (mfk * 16 + r16) * 64 + kk * 32 + g * 8);

    const short* qsp = q_s + (size_t)bh * 2048 * 64;
    float dacc[2][4] = {};
    const f32x4 z4 = {0.f, 0.f, 0.f, 0.f};

    if (nUr > 0) {
        stage64x128(qsp, 64, &lQ[0][0], tid);
        int buf = 0;
        for (int qb = 0; qb < nUr; qb += 64) {
            __syncthreads();
            if (qb + 64 < nUr)
                stage64x128(qsp + (size_t)(qb + 64) * 64, 64, &lQ[buf ^ 1][0], tid);
            const short* Qc = &lQ[buf][0];
#pragma unroll
            for (int nf = 0; nf < 4; nf++) {
                float fm = (qb + nf * 16 + r16 < n) ? 1.0f : 0.0f;
                frag8 bq0 = ldswz(Qc, nf * 16 + r16, g);
                frag8 bq1 = ldswz(Qc, nf * 16 + r16, 4 + g);
#pragma unroll
                for (int mfk = 0; mfk < 2; mfk++) {
                    f32x4 s = MFMA16(kf[mfk][0], bq0, z4, 0, 0, 0);
                    s = MFMA16(kf[mfk][1], bq1, s, 0, 0, 0);
#pragma unroll
                    for (int r = 0; r < 4; r++)
                        dacc[mfk][r] += fm * EXP2F(s[r]);
                }
            }
            buf ^= 1;
        }
    }
#pragma unroll
    for (int mfk = 0; mfk < 2; mfk++)
#pragma unroll
        for (int r = 0; r < 4; r++) {
            float v = dacc[mfk][r];
#pragma unroll
            for (int off = 1; off < 16; off <<= 1)
                v += __shfl_xor(v, off, 16);
            dacc[mfk][r] = v;
        }
    if (r16 == 0) {
#pragma unroll
        for (int mfk = 0; mfk < 2; mfk++)
#pragma unroll
            for (int r = 0; r < 4; r++)
                lD[w * 32 + mfk * 16 + g * 4 + r] = RCPF(dacc[mfk][r]);
    }
    // stage v tile [128 k][64 d] into lT (stride 70)
    const short* vrow = v_s + ((size_t)bh * 2048 + kt * 128) * 64;
#pragma unroll
    for (int i = 0; i < 8; i++) {
        int idx4 = i * 256 + tid;               // 4-short units, 0..2047
        int row = idx4 >> 4, c4 = idx4 & 15;
        uint2 u = *(const uint2*)(vrow + (size_t)row * 64 + c4 * 4);
        *(uint32_t*)&lT[row * 70 + c4 * 4]     = u.x;
        *(uint32_t*)&lT[row * 70 + c4 * 4 + 2] = u.y;
    }
    __syncthreads();
    // transposed write: vhatT[bh][d][kt*128 + kc*32 .. +32]
    {
        int d = tid >> 2, kc = tid & 3;
        short* dstp = vhatT + ((size_t)bh * 64 + d) * 2048 + kt * 128 + kc * 32;
        uint32_t wd[16];
#pragma unroll
        for (int j2 = 0; j2 < 16; j2++) {
            int k0 = kc * 32 + j2 * 2;
            float v0 = bf2f(lT[k0 * 70 + d]) * lD[k0];
            float v1 = bf2f(lT[(k0 + 1) * 70 + d]) * lD[k0 + 1];
            wd[j2] = pack2bf(v0, v1);
        }
#pragma unroll
        for (int j4 = 0; j4 < 4; j4++) {
            uint4 o = {wd[j4 * 4], wd[j4 * 4 + 1], wd[j4 * 4 + 2], wd[j4 * 4 + 3]};
            *((uint4*)dstp + j4) = o;
        }
    }
}

// ---------- K4: apply; wave owns 32 q (128 q / block), split-2 over k ----------
// Output rows stay COMPACTED; scatter deferred to k_final.
__global__ __launch_bounds__(256, 3) void k_apply(const short* __restrict__ q_s,
                                                  const short* __restrict__ k_s,
                                                  const short* __restrict__ vhatT,
                                                  const int* __restrict__ nU,
                                                  short* __restrict__ p0,
                                                  short* __restrict__ p1) {
    __shared__ short lK[2][4096];
    __shared__ short lV[2][4096];
    __shared__ short lP[128 * 64];              // P[q][k] bf16, chunk-XOR swizzled
    const int wg = blockIdx.x;                  // 1024 blocks
    const int x = wg & 7, r2 = wg >> 3;
    const int qt = r2 & 15, y = r2 >> 4;        // y 0..7
    const int bhsp = (y << 3) | x;              // qt-blocks of (bh,sp) share an XCD
    const int bh = bhsp >> 1, sp = bhsp & 1;
    const int b = bh >> 4, h = bh & 15;
    const int n = nU[b];
    if (qt * 128 >= n) return;                  // uniform early exit
    const int tid = threadIdx.x, w = tid >> 6, ln = tid & 63;
    const int r16 = ln & 15, g = ln >> 4;

    const short* qp = q_s + ((size_t)bh * 2048 + qt * 128 + w * 32) * 64;
    frag8 qf[2][2];
#pragma unroll
    for (int qi = 0; qi < 2; qi++)
#pragma unroll
        for (int kk = 0; kk < 2; kk++)
            qf[qi][kk] = *(const frag8*)(qp + (qi * 16 + r16) * 64 + kk * 32 + g * 8);

    const short* kp = k_s + ((size_t)bh * 2048 + sp * 1024) * 64;
    const short* vp = vhatT + (size_t)bh * 64 * 2048 + sp * 1024;

    f32x4 oacc[2][4] = {};
    const f32x4 z4 = {0.f, 0.f, 0.f, 0.f};

    stage64x128(kp, 64, &lK[0][0], tid);
    stage64x128(vp, 2048, &lV[0][0], tid);
    int buf = 0;
    for (int kb = 0; kb < 1024; kb += 64) {
        __syncthreads();
        if (kb + 64 < 1024) {
            stage64x128(kp + (size_t)(kb + 64) * 64, 64, &lK[buf ^ 1][0], tid);
            stage64x128(vp + kb + 64, 2048, &lV[buf ^ 1][0], tid);
        }
        const short* Kc = &lK[buf][0];
        const short* Vc = &lV[buf][0];
        // hoist V fragment reads (independent of QK^T chain)
        frag8 vb[4][2];
#pragma unroll
        for (int nf = 0; nf < 4; nf++)
#pragma unroll
            for (int kk = 0; kk < 2; kk++)
                vb[nf][kk] = ldswz(Vc, nf * 16 + r16, kk * 4 + g);
        // S^T (64k x 32q per wave) -> exp2 -> P[q][k]
#pragma unroll
        for (int qi = 0; qi < 2; qi++) {
            const int prow = w * 32 + qi * 16 + r16;
            const int rx = prow & 7;
#pragma unroll
            for (int mf2 = 0; mf2 < 4; mf2++) {
                f32x4 s = z4;
#pragma unroll
                for (int kk = 0; kk < 2; kk++)
                    s = MFMA16(ldswz(Kc, mf2 * 16 + r16, kk * 4 + g), qf[qi][kk], s, 0, 0, 0);
                float e0 = EXP2F(s[0]), e1 = EXP2F(s[1]);
                float e2 = EXP2F(s[2]), e3 = EXP2F(s[3]);
                uint2 pk;
                pk.x = pack2bf(e0, e1);
                pk.y = pack2bf(e2, e3);
                int o = mf2 * 32 + g * 8;       // byte offset in 128B P row
                int addr = prow * 128 + (((o >> 4) ^ rx) << 4) + (o & 15);
                *(uint2*)((char*)lP + addr) = pk;
            }
        }
        // PV: oacc[qi][d] += P[q][k] * vhat[d][k]  (same-wave P RAW: DS in-order)
#pragma unroll
        for (int qi = 0; qi < 2; qi++) {
            const int prow = w * 32 + qi * 16 + r16;
            const int rx = prow & 7;
            frag8 pa[2];
#pragma unroll
            for (int kk = 0; kk < 2; kk++)
                pa[kk] = *(const frag8*)((char*)lP + prow * 128 + (((kk * 4 + g) ^ rx) << 4));
#pragma unroll
            for (int nf = 0; nf < 4; nf++)
#pragma unroll
                for (int kk = 0; kk < 2; kk++)
                    oacc[qi][nf] = MFMA16(pa[kk], vb[nf][kk], oacc[qi][nf], 0, 0, 0);
        }
        buf ^= 1;
    }
    // epilogue: store compacted rows (coalesced); rows >= n guarded
    short* op = sp ? p1 : p0;
#pragma unroll
    for (int qi = 0; qi < 2; qi++)
#pragma unroll
        for (int r = 0; r < 4; r++) {
            int lq = qt * 128 + w * 32 + qi * 16 + g * 4 + r;
            if (lq < n) {
#pragma unroll
                for (int nf = 0; nf < 4; nf++) {
                    int d = nf * 16 + r16;
                    op[((size_t)(b * 2048 + lq)) * 1024 + h * 64 + d] = f2bf(oacc[qi][nf][r]);
                }
            }
        }
}

// ---------- K5: out = attn_c @ Wo^T + b_O + Q, scatter rows via idx ----------
// 128x64 tiles, grid 512; wg%8 groups tn-blocks of a tm per XCD; dead tiles skipped.
__global__ __launch_bounds__(256) void k_final(const short* __restrict__ A,
                                               const short* __restrict__ Bt,
                                               const float* __restrict__ bias,
                                               const float* __restrict__ Qres,
                                               const int* __restrict__ idx,
                                               const int* __restrict__ nU,
                                               float* __restrict__ out) {
    __shared__ short lA[2][4096];
    __shared__ short lB[2][2048];
    const int wg = blockIdx.x;                 // 512 blocks
    const int x = wg & 7, r2 = wg >> 3;
    const int tnb = r2 & 15, tmh = r2 >> 4;    // tnb 0..15, tmh 0..3
    const int tmb = x | (tmh << 3);            // 0..31
    const int bb = tmb >> 4;
    const int n = nU[bb];
    if ((tmb & 15) * 128 >= n) return;         // dead (masked) tile
    const int tid = threadIdx.x, w = tid >> 6, ln = tid & 63;
    const int wm = w >> 1, wn = w & 1, r16 = ln & 15, g = ln >> 4;
    const int tn = tnb * 64, tm = tmb * 128;
    const short* Ab = A + (size_t)tm * 1024;
    const short* Bb = Bt + (size_t)tn * 1024;

    f32x4 acc[4][2] = {};
    stage_gswz(Ab, &lA[0][0], tid);
    stage_gswz64(Bb, &lB[0][0], tid);
    int buf = 0;
    for (int ks = 0; ks < 32; ks++) {
        __syncthreads();
        if (ks + 1 < 32) {
            stage_gswz(Ab + (ks + 1) * 32, &lA[buf ^ 1][0], tid);
            stage_gswz64(Bb + (ks + 1) * 32, &lB[buf ^ 1][0], tid);
        }
        frag8 af[4], bg[2];
#pragma unroll
        for (int mf = 0; mf < 4; mf++)
            af[mf] = ldgswz(&lA[buf][0], wm * 64 + mf * 16 + r16, g);
#pragma unroll
        for (int nf = 0; nf < 2; nf++)
            bg[nf] = ldgswz(&lB[buf][0], wn * 32 + nf * 16 + r16, g);
#pragma unroll
        for (int mf = 0; mf < 4; mf++)
#pragma unroll
            for (int nf = 0; nf < 2; nf++)
                acc[mf][nf] = MFMA16(af[mf], bg[nf], acc[mf][nf], 0, 0, 0);
        buf ^= 1;
    }
#pragma unroll
    for (int mf = 0; mf < 4; mf++)
#pragma unroll
        for (int r = 0; r < 4; r++) {
            int m = tm + wm * 64 + mf * 16 + g * 4 + r;
            int i = m & 2047;
            if (i < n) {
                int qg = idx[bb * 2048 + i];
                size_t rowo = ((size_t)(bb * 2048 + qg)) * 1024;
#pragma unroll
                for (int nf = 0; nf < 2; nf++) {
                    int nn = tn + wn * 32 + nf * 16 + r16;
                    float val = acc[mf][nf][r] + bias[nn] + Qres[rowo + nn];
                    out[rowo + nn] = val;
                }
            }
        }
}

// ---------- launch ----------
extern "C" void kernel_launch(void* const* d_in, const int* in_sizes, int n_in,
                              void* d_out, int out_size, void* d_ws, size_t ws_size,
                              hipStream_t stream) {
    (void)in_sizes; (void)n_in; (void)out_size; (void)ws_size;
    const float* Qf  = (const float*)d_in[0];
    const float* Kf  = (const float*)d_in[1];
    const float* Vf  = (const float*)d_in[2];
    const int*   msk = (const int*)d_in[3];
    const float* WQ  = (const float*)d_in[4];
    const float* bQ  = (const float*)d_in[5];
    const float* WK  = (const float*)d_in[6];
    const float* bK  = (const float*)d_in[7];
    const float* WV  = (const float*)d_in[8];
    const float* bV  = (const float*)d_in[9];
    const float* WO  = (const float*)d_in[10];
    const float* bO  = (const float*)d_in[11];
    float* out = (float*)d_out;

    char* p = (char*)d_ws;
    const size_t SZ_ACT = (size_t)4096 * 1024 * 2;  // 8 MB bf16
    const size_t SZ_W   = (size_t)1024 * 1024 * 2;  // 2 MB
    short* Qb  = (short*)p; p += SZ_ACT;
    short* Kb  = (short*)p; p += SZ_ACT;
    short* Vb  = (short*)p; p += SZ_ACT;
    short* q_s = (short*)p; p += SZ_ACT;            // compacted q projections
    short* k_s = (short*)p; p += SZ_ACT;
    short* v_s = (short*)p; p += SZ_ACT;
    short* Wqb = (short*)p; p += SZ_W;
    short* Wkb = (short*)p; p += SZ_W;
    short* Wvb = (short*)p; p += SZ_W;
    short* Wob = (short*)p; p += SZ_W;
    int* idx  = (int*)p; p += (size_t)2 * 2048 * 4;
    int* invp = (int*)p; p += (size_t)2 * 2048 * 4;
    int* nU   = (int*)p; p += 256;
    short* vhatT = Qb;   // dead after proj3
    short* p0    = Kb;   // dead after proj3
    short* p1    = Vb;   // dead after proj3

    // compaction (mask-only dependency)
    k_compact<<<2, 64, 0, stream>>>(msk, idx, invp, nU);

    // fused converts: activations + weights -> bf16 (Q rows permuted; dead rows skipped)
    k_cvt_all<<<4096, 256, 0, stream>>>(Qf, Kf, Vf, WQ, WK, WV, WO, invp, nU,
                                        Qb, Kb, Vb, Wqb, Wkb, Wvb, Wob);

    // fused projections (z: 0=Q scaled+compacted, 1=K, 2=V); XCD tm-swizzle
    k_proj3<<<768, 256, 0, stream>>>(Qb, Kb, Vb, Wqb, Wkb, Wvb,
                                     bQ, bK, bV, nU, q_s, k_s, v_s);

    // column softmax denominators + fused v-scale/transpose (128 k / block)
    k_stats<<<512, 256, 0, stream>>>(k_s, q_s, nU, v_s, vhatT);

    // attention apply, 32 q / wave, split-2 over k, compacted output
    k_apply<<<1024, 256, 0, stream>>>(q_s, k_s, vhatT, nU, p0, p1);

    // sum partials into p0 + fill masked output rows (fused)
    k_psum2m<<<2048, 256, 0, stream>>>(p0, p1, msk, bO, Qf, out);

    // output projection + bias + residual, scatter via idx (dead tiles skipped)
    k_final<<<512, 256, 0, stream>>>(p0, Wob, bO, Qf, idx, nU, out);
}

// Round 13
// 150.094 us; speedup vs baseline: 1.0451x; 1.0112x over previous
//
#include <hip/hip_runtime.h>
#include <hip/hip_bf16.h>
#include <stdint.h>

// ---------- types ----------
using frag8 = __attribute__((ext_vector_type(8))) short;   // 8 bf16 (4 VGPRs)
using f32x4 = __attribute__((ext_vector_type(4))) float;   // 4 fp32 acc

#define MFMA16 __builtin_amdgcn_mfma_f32_16x16x32_bf16

#if __has_builtin(__builtin_amdgcn_exp2f)
#define EXP2F(x) __builtin_amdgcn_exp2f(x)
#else
#define EXP2F(x) __expf((x) * 0.6931471805599453f)
#endif
#if __has_builtin(__builtin_amdgcn_rcpf)
#define RCPF(x) __builtin_amdgcn_rcpf(x)
#else
#define RCPF(x) (1.0f / (x))
#endif

// S' = (q.k)/8 * log2(e): folded into Q projection output
#define SCALE_Q 0.18033688011112042f

__device__ __forceinline__ short f2bf(float f) {
    union { __hip_bfloat16 h; short s; } c;
    c.h = __float2bfloat16(f);               // HW cvt
    return c.s;
}
__device__ __forceinline__ float bf2f(short s) {
    union { uint32_t u; float f; } x; x.u = ((uint32_t)(uint16_t)s) << 16;
    return x.f;
}
__device__ __forceinline__ uint32_t pack2bf(float a, float b) {
    float2 t; t.x = a; t.y = b;
    __hip_bfloat162 h = __float22bfloat162_rn(t);   // HW v_cvt_pk_bf16_f32
    union { __hip_bfloat162 h; uint32_t u; } c; c.h = h;
    return c.u;
}
__device__ __forceinline__ uint32_t addpk(uint32_t a, uint32_t b) {
    float a0 = bf2f((short)(a & 0xffff)), a1 = bf2f((short)(a >> 16));
    float b0 = bf2f((short)(b & 0xffff)), b1 = bf2f((short)(b >> 16));
    return pack2bf(a0 + b0, a1 + b1);
}

// ---------- K_compact: compaction + inverse permutation ----------
__global__ __launch_bounds__(64) void k_compact(const int* __restrict__ mask,
                                                int* __restrict__ idx,
                                                int* __restrict__ invp,
                                                int* __restrict__ nU) {
    const int b = blockIdx.x, ln = threadIdx.x;
    const int* m = mask + b * 2048;
    int tot = 0;
    for (int c = 0; c < 32; c++)
        tot += __popcll(__ballot(m[c * 64 + ln] != 0));
    int base = 0, mbase = tot;
    for (int c = 0; c < 32; c++) {
        int i = c * 64 + ln;
        int mv = m[i];
        unsigned long long bal = __ballot(mv != 0);
        int rank = __popcll(bal & ((1ull << ln) - 1ull));
        int nb = __popcll(bal);
        int pos = mv ? (base + rank) : (mbase + ln - rank);
        invp[b * 2048 + i] = pos;
        if (mv) idx[b * 2048 + pos] = i;
        base += nb; mbase += 64 - nb;
    }
    if (ln == 0) nU[b] = tot;
}

// ---------- K_psum2m: p0 += p1, then masked-row output fill (fused) ----------
__global__ __launch_bounds__(256) void k_psum2m(short* __restrict__ p0,
                                                const short* __restrict__ p1,
                                                const int* __restrict__ mask,
                                                const float* __restrict__ bO,
                                                const float* __restrict__ Qf,
                                                float* __restrict__ out) {
    const int n16 = 524288;                              // uint4 count (8MB bf16)
    int i0 = blockIdx.x * 256 + threadIdx.x;
    int st = gridDim.x * 256;
    for (int i = i0; i < n16; i += st) {
        uint4 a = ((const uint4*)p0)[i];
        uint4 b = ((const uint4*)p1)[i];
        uint4 r;
        r.x = addpk(a.x, b.x); r.y = addpk(a.y, b.y);
        r.z = addpk(a.z, b.z); r.w = addpk(a.w, b.w);
        ((uint4*)p0)[i] = r;
    }
    const int total = 4096 * 256;                        // float4 count of out
    for (int i = i0; i < total; i += st) {
        int row = i >> 8, c4 = i & 255;
        if (mask[row] == 0) {
            float4 q = ((const float4*)Qf)[i];
            float4 bv = ((const float4*)bO)[c4];
            float4 o; o.x = q.x + bv.x; o.y = q.y + bv.y;
            o.z = q.z + bv.z; o.w = q.w + bv.w;
            ((float4*)out)[i] = o;
        }
    }
}

// ---------- fused fp32 -> bf16 convert (7 segments; Q rows permuted) ----------
__global__ __launch_bounds__(256) void k_cvt_all(
    const float* __restrict__ s0, const float* __restrict__ s1,
    const float* __restrict__ s2, const float* __restrict__ s3,
    const float* __restrict__ s4, const float* __restrict__ s5,
    const float* __restrict__ s6, const int* __restrict__ invp,
    const int* __restrict__ nU,
    short* __restrict__ d0, short* __restrict__ d1, short* __restrict__ d2,
    short* __restrict__ d3, short* __restrict__ d4, short* __restrict__ d5,
    short* __restrict__ d6) {
    const int A4 = 1048576, W4 = 262144;       // float4 counts
    int i = blockIdx.x * 256 + threadIdx.x;
    int st = gridDim.x * 256;
    const int total = 3 * A4 + 4 * W4;
    for (; i < total; i += st) {
        const float* s; short* d; int j;
        bool permQ = false;
        if (i < A4)            { s = s0; d = d0; j = i; permQ = true; }
        else if (i < 2 * A4)   { s = s1; d = d1; j = i - A4; }
        else if (i < 3 * A4)   { s = s2; d = d2; j = i - 2 * A4; }
        else {
            int t = i - 3 * A4; int seg = t / W4; j = t - seg * W4;
            s = seg == 0 ? s3 : seg == 1 ? s4 : seg == 2 ? s5 : s6;
            d = seg == 0 ? d3 : seg == 1 ? d4 : seg == 2 ? d5 : d6;
        }
        int jd = j;
        if (permQ) {
            int row = j >> 8, c4 = j & 255;
            int pos = invp[row];
            if (pos >= nU[row >> 11]) continue;         // dead Q row: skip
            int nrow = (row & ~2047) + pos;             // compacted row, same batch
            jd = (nrow << 8) + c4;
        }
        float4 v = reinterpret_cast<const float4*>(s)[j];
        uint2 o;
        o.x = pack2bf(v.x, v.y);
        o.y = pack2bf(v.z, v.w);
        reinterpret_cast<uint2*>(d)[jd] = o;
    }
}

// ---------- swizzled staging: [64 rows][128B], XOR chunk ^= row&7 ----------
__device__ __forceinline__ void stage64x128(const short* __restrict__ g, int rs,
                                            short* lds, int tid) {
#pragma unroll
    for (int j = 0; j < 2; j++) {
        int chunk = j * 256 + tid;            // 0..511
        int row = chunk >> 3, c = chunk & 7;
        int sc = c ^ (row & 7);
        __builtin_amdgcn_global_load_lds(
            (const __attribute__((address_space(1))) uint32_t*)(g + (size_t)row * rs + sc * 8),
            (__attribute__((address_space(3))) uint32_t*)(lds + (j * 256 + (tid & 192)) * 8),
            16, 0, 0);
    }
}
// swizzled b128 read: logical (row, 16B-chunk cc)
__device__ __forceinline__ frag8 ldswz(const short* lds, int row, int cc) {
    return *(const frag8*)(lds + row * 64 + ((cc ^ (row & 7)) << 3));
}

// ---------- GEMM tile staging: [128 rows][32 cols] packed as 64 paired-rows ----------
__device__ __forceinline__ void stage_gswz(const short* __restrict__ g,
                                           short* lds, int tid) {
#pragma unroll
    for (int j = 0; j < 2; j++) {
        int c = j * 256 + tid;                // 0..511
        int lrow = c >> 3;
        int sc = (c & 7) ^ (lrow & 7);
        int grow = lrow * 2 + (sc >> 2);
        int gcol = (sc & 3) * 8;
        __builtin_amdgcn_global_load_lds(
            (const __attribute__((address_space(1))) uint32_t*)(g + (size_t)grow * 1024 + gcol),
            (__attribute__((address_space(3))) uint32_t*)(lds + (j * 256 + (tid & 192)) * 8),
            16, 0, 0);
    }
}
// 64-row variant: [64 rows][32 cols], 256 chunks, one per thread
__device__ __forceinline__ void stage_gswz64(const short* __restrict__ g,
                                             short* lds, int tid) {
    int c = tid;                              // 0..255
    int lrow = c >> 3;
    int sc = (c & 7) ^ (lrow & 7);
    int grow = lrow * 2 + (sc >> 2);
    int gcol = (sc & 3) * 8;
    __builtin_amdgcn_global_load_lds(
        (const __attribute__((address_space(1))) uint32_t*)(g + (size_t)grow * 1024 + gcol),
        (__attribute__((address_space(3))) uint32_t*)(lds + (tid & 192) * 8),
        16, 0, 0);
}
__device__ __forceinline__ frag8 ldgswz(const short* lds, int row, int cc) {
    int lrow = row >> 1;
    int s = (((row & 1) << 2) + cc) ^ (lrow & 7);
    return *(const frag8*)(lds + lrow * 64 + s * 8);
}

// ---------- K1: fused QKV projection ----------
// grid flat 768; wg%8 == tm low bits (XCD A-reuse).
// z==0 (Q): A rows are pre-compacted; tiles beyond ceil(n/128) skipped.
__global__ __launch_bounds__(256) void k_proj3(
    const short* __restrict__ A0, const short* __restrict__ A1, const short* __restrict__ A2,
    const short* __restrict__ B0, const short* __restrict__ B1, const short* __restrict__ B2,
    const float* __restrict__ bias0, const float* __restrict__ bias1, const float* __restrict__ bias2,
    const int* __restrict__ nU,
    short* __restrict__ dst0, short* __restrict__ dst1, short* __restrict__ dst2) {
    __shared__ short lA[2][4096];
    __shared__ short lB[2][4096];
    const int wg = blockIdx.x;
    const int tmlow = wg & 7, tnb = (wg >> 3) & 7, rest = wg >> 6;
    const int tmh = rest & 3, z = rest >> 2;    // z 0..2
    const int tmb = tmlow | (tmh << 3);         // 0..31
    if (z == 0 && (tmb & 15) * 128 >= nU[tmb >> 4]) return;  // dead Q tile
    const short* A  = z == 0 ? A0 : z == 1 ? A1 : A2;
    const short* Bt = z == 0 ? B0 : z == 1 ? B1 : B2;
    const float* bias = z == 0 ? bias0 : z == 1 ? bias1 : bias2;
    short* dst = z == 0 ? dst0 : z == 1 ? dst1 : dst2;
    const float scale = z == 0 ? SCALE_Q : 1.0f;

    const int tid = threadIdx.x, w = tid >> 6, ln = tid & 63;
    const int wm = w >> 1, wn = w & 1, r16 = ln & 15, g = ln >> 4;
    const int tn = tnb * 128, tm = tmb * 128;
    const short* Ab = A + (size_t)tm * 1024;
    const short* Bb = Bt + (size_t)tn * 1024;

    f32x4 acc[4][4] = {};
    stage_gswz(Ab, &lA[0][0], tid);
    stage_gswz(Bb, &lB[0][0], tid);
    int buf = 0;
    for (int ks = 0; ks < 32; ks++) {
        __syncthreads();
        if (ks + 1 < 32) {
            stage_gswz(Ab + (ks + 1) * 32, &lA[buf ^ 1][0], tid);
            stage_gswz(Bb + (ks + 1) * 32, &lB[buf ^ 1][0], tid);
        }
        frag8 af[4], bg[4];
#pragma unroll
        for (int mf = 0; mf < 4; mf++)
            af[mf] = ldgswz(&lA[buf][0], wm * 64 + mf * 16 + r16, g);
#pragma unroll
        for (int nf = 0; nf < 4; nf++)
            bg[nf] = ldgswz(&lB[buf][0], wn * 64 + nf * 16 + r16, g);
#pragma unroll
        for (int mf = 0; mf < 4; mf++)
#pragma unroll
            for (int nf = 0; nf < 4; nf++)
                acc[mf][nf] = MFMA16(af[mf], bg[nf], acc[mf][nf], 0, 0, 0);
        buf ^= 1;
    }
#pragma unroll
    for (int mf = 0; mf < 4; mf++)
#pragma unroll
        for (int r = 0; r < 4; r++) {
            int m = tm + wm * 64 + mf * 16 + g * 4 + r;
            int b = m >> 11, seq = m & 2047;
#pragma unroll
            for (int nf = 0; nf < 4; nf++) {
                int n = tn + wn * 64 + nf * 16 + r16;
                float val = (acc[mf][nf][r] + bias[n]) * scale;
                int h = n >> 6, d = n & 63;
                dst[((size_t)(b * 16 + h) * 2048 + seq) * 64 + d] = f2bf(val);
            }
        }
}

// ---------- K2: stats + fused v-scale; wave owns 32 k (128 k / block) ----------
__global__ __launch_bounds__(256, 3) void k_stats(const short* __restrict__ k_s,
                                                  const short* __restrict__ q_s,
                                                  const int* __restrict__ nU,
                                                  const short* __restrict__ v_s,
                                                  short* __restrict__ vhatT) {
    __shared__ short lQ[2][4096];
    __shared__ float lD[128];
    __shared__ short lT[128 * 70];              // v tile [k][d], row stride 70
    const int wg = blockIdx.x;                  // 512 blocks
    const int x = wg & 7, r2 = wg >> 3;
    const int kt = r2 & 15;                     // 16 kt tiles of 128 k
    const int bh = x + 8 * (r2 >> 4);           // bh-grouped per XCD
    const int b = bh >> 4;
    const int n = nU[b], nUr = (n + 63) & ~63;
    const int tid = threadIdx.x, w = tid >> 6, ln = tid & 63;
    const int r16 = ln & 15, g = ln >> 4;
    const int kbase = kt * 128 + w * 32;

    const short* kp = k_s + ((size_t)bh * 2048 + kbase) * 64;
    frag8 kf[2][2];
#pragma unroll
    for (int mfk = 0; mfk < 2; mfk++)
#pragma unroll
        for (int kk = 0; kk < 2; kk++)
            kf[mfk][kk] = *(const frag8*)(kp + (mfk * 16 + r16) * 64 + kk * 32 + g * 8);

    const short* qsp = q_s + (size_t)bh * 2048 * 64;
    float dacc[2][4] = {};
    const f32x4 z4 = {0.f, 0.f, 0.f, 0.f};

    if (nUr > 0) {
        stage64x128(qsp, 64, &lQ[0][0], tid);
        int buf = 0;
        for (int qb = 0; qb < nUr; qb += 64) {
            __syncthreads();
            if (qb + 64 < nUr)
                stage64x128(qsp + (size_t)(qb + 64) * 64, 64, &lQ[buf ^ 1][0], tid);
            const short* Qc = &lQ[buf][0];
#pragma unroll
            for (int nf = 0; nf < 4; nf++) {
                float fm = (qb + nf * 16 + r16 < n) ? 1.0f : 0.0f;
                frag8 bq0 = ldswz(Qc, nf * 16 + r16, g);
                frag8 bq1 = ldswz(Qc, nf * 16 + r16, 4 + g);
#pragma unroll
                for (int mfk = 0; mfk < 2; mfk++) {
                    f32x4 s = MFMA16(kf[mfk][0], bq0, z4, 0, 0, 0);
                    s = MFMA16(kf[mfk][1], bq1, s, 0, 0, 0);
#pragma unroll
                    for (int r = 0; r < 4; r++)
                        dacc[mfk][r] += fm * EXP2F(s[r]);
                }
            }
            buf ^= 1;
        }
    }
#pragma unroll
    for (int mfk = 0; mfk < 2; mfk++)
#pragma unroll
        for (int r = 0; r < 4; r++) {
            float v = dacc[mfk][r];
#pragma unroll
            for (int off = 1; off < 16; off <<= 1)
                v += __shfl_xor(v, off, 16);
            dacc[mfk][r] = v;
        }
    if (r16 == 0) {
#pragma unroll
        for (int mfk = 0; mfk < 2; mfk++)
#pragma unroll
            for (int r = 0; r < 4; r++)
                lD[w * 32 + mfk * 16 + g * 4 + r] = RCPF(dacc[mfk][r]);
    }
    // stage v tile [128 k][64 d] into lT (stride 70)
    const short* vrow = v_s + ((size_t)bh * 2048 + kt * 128) * 64;
#pragma unroll
    for (int i = 0; i < 8; i++) {
        int idx4 = i * 256 + tid;               // 4-short units, 0..2047
        int row = idx4 >> 4, c4 = idx4 & 15;
        uint2 u = *(const uint2*)(vrow + (size_t)row * 64 + c4 * 4);
        *(uint32_t*)&lT[row * 70 + c4 * 4]     = u.x;
        *(uint32_t*)&lT[row * 70 + c4 * 4 + 2] = u.y;
    }
    __syncthreads();
    // transposed write: vhatT[bh][d][kt*128 + kc*32 .. +32]
    {
        int d = tid >> 2, kc = tid & 3;
        short* dstp = vhatT + ((size_t)bh * 64 + d) * 2048 + kt * 128 + kc * 32;
        uint32_t wd[16];
#pragma unroll
        for (int j2 = 0; j2 < 16; j2++) {
            int k0 = kc * 32 + j2 * 2;
            float v0 = bf2f(lT[k0 * 70 + d]) * lD[k0];
            float v1 = bf2f(lT[(k0 + 1) * 70 + d]) * lD[k0 + 1];
            wd[j2] = pack2bf(v0, v1);
        }
#pragma unroll
        for (int j4 = 0; j4 < 4; j4++) {
            uint4 o = {wd[j4 * 4], wd[j4 * 4 + 1], wd[j4 * 4 + 2], wd[j4 * 4 + 3]};
            *((uint4*)dstp + j4) = o;
        }
    }
}

// ---------- K4: apply; wave owns 32 q (128 q / block), split-2 over k ----------
// Output rows stay COMPACTED; scatter deferred to k_final.
// K-fragments hoisted out of the qi loop (compiler can't CSE across lP stores).
__global__ __launch_bounds__(256, 3) void k_apply(const short* __restrict__ q_s,
                                                  const short* __restrict__ k_s,
                                                  const short* __restrict__ vhatT,
                                                  const int* __restrict__ nU,
                                                  short* __restrict__ p0,
                                                  short* __restrict__ p1) {
    __shared__ short lK[2][4096];
    __shared__ short lV[2][4096];
    __shared__ short lP[128 * 64];              // P[q][k] bf16, chunk-XOR swizzled
    const int wg = blockIdx.x;                  // 1024 blocks
    const int x = wg & 7, r2 = wg >> 3;
    const int qt = r2 & 15, y = r2 >> 4;        // y 0..7
    const int bhsp = (y << 3) | x;              // qt-blocks of (bh,sp) share an XCD
    const int bh = bhsp >> 1, sp = bhsp & 1;
    const int b = bh >> 4, h = bh & 15;
    const int n = nU[b];
    if (qt * 128 >= n) return;                  // uniform early exit
    const int tid = threadIdx.x, w = tid >> 6, ln = tid & 63;
    const int r16 = ln & 15, g = ln >> 4;

    const short* qp = q_s + ((size_t)bh * 2048 + qt * 128 + w * 32) * 64;
    frag8 qf[2][2];
#pragma unroll
    for (int qi = 0; qi < 2; qi++)
#pragma unroll
        for (int kk = 0; kk < 2; kk++)
            qf[qi][kk] = *(const frag8*)(qp + (qi * 16 + r16) * 64 + kk * 32 + g * 8);

    const short* kp = k_s + ((size_t)bh * 2048 + sp * 1024) * 64;
    const short* vp = vhatT + (size_t)bh * 64 * 2048 + sp * 1024;

    f32x4 oacc[2][4] = {};
    const f32x4 z4 = {0.f, 0.f, 0.f, 0.f};

    stage64x128(kp, 64, &lK[0][0], tid);
    stage64x128(vp, 2048, &lV[0][0], tid);
    int buf = 0;
    for (int kb = 0; kb < 1024; kb += 64) {
        __syncthreads();
        if (kb + 64 < 1024) {
            stage64x128(kp + (size_t)(kb + 64) * 64, 64, &lK[buf ^ 1][0], tid);
            stage64x128(vp + kb + 64, 2048, &lV[buf ^ 1][0], tid);
        }
        const short* Kc = &lK[buf][0];
        const short* Vc = &lV[buf][0];
        // hoist K and V fragment reads (shared across qi; independent of QK^T chain)
        frag8 kfr[4][2], vb[4][2];
#pragma unroll
        for (int mf2 = 0; mf2 < 4; mf2++)
#pragma unroll
            for (int kk = 0; kk < 2; kk++)
                kfr[mf2][kk] = ldswz(Kc, mf2 * 16 + r16, kk * 4 + g);
#pragma unroll
        for (int nf = 0; nf < 4; nf++)
#pragma unroll
            for (int kk = 0; kk < 2; kk++)
                vb[nf][kk] = ldswz(Vc, nf * 16 + r16, kk * 4 + g);
        // S^T (64k x 32q per wave) -> exp2 -> P[q][k]
#pragma unroll
        for (int qi = 0; qi < 2; qi++) {
            const int prow = w * 32 + qi * 16 + r16;
            const int rx = prow & 7;
#pragma unroll
            for (int mf2 = 0; mf2 < 4; mf2++) {
                f32x4 s = z4;
#pragma unroll
                for (int kk = 0; kk < 2; kk++)
                    s = MFMA16(kfr[mf2][kk], qf[qi][kk], s, 0, 0, 0);
                float e0 = EXP2F(s[0]), e1 = EXP2F(s[1]);
                float e2 = EXP2F(s[2]), e3 = EXP2F(s[3]);
                uint2 pk;
                pk.x = pack2bf(e0, e1);
                pk.y = pack2bf(e2, e3);
                int o = mf2 * 32 + g * 8;       // byte offset in 128B P row
                int addr = prow * 128 + (((o >> 4) ^ rx) << 4) + (o & 15);
                *(uint2*)((char*)lP + addr) = pk;
            }
        }
        // PV: oacc[qi][d] += P[q][k] * vhat[d][k]  (same-wave P RAW: DS in-order)
#pragma unroll
        for (int qi = 0; qi < 2; qi++) {
            const int prow = w * 32 + qi * 16 + r16;
            const int rx = prow & 7;
            frag8 pa[2];
#pragma unroll
            for (int kk = 0; kk < 2; kk++)
                pa[kk] = *(const frag8*)((char*)lP + prow * 128 + (((kk * 4 + g) ^ rx) << 4));
#pragma unroll
            for (int nf = 0; nf < 4; nf++)
#pragma unroll
                for (int kk = 0; kk < 2; kk++)
                    oacc[qi][nf] = MFMA16(pa[kk], vb[nf][kk], oacc[qi][nf], 0, 0, 0);
        }
        buf ^= 1;
    }
    // epilogue: store compacted rows (coalesced); rows >= n guarded
    short* op = sp ? p1 : p0;
#pragma unroll
    for (int qi = 0; qi < 2; qi++)
#pragma unroll
        for (int r = 0; r < 4; r++) {
            int lq = qt * 128 + w * 32 + qi * 16 + g * 4 + r;
            if (lq < n) {
#pragma unroll
                for (int nf = 0; nf < 4; nf++) {
                    int d = nf * 16 + r16;
                    op[((size_t)(b * 2048 + lq)) * 1024 + h * 64 + d] = f2bf(oacc[qi][nf][r]);
                }
            }
        }
}

// ---------- K5: out = attn_c @ Wo^T + b_O + Q, scatter rows via idx ----------
// 128x64 tiles, grid 512; wg%8 groups tn-blocks of a tm per XCD; dead tiles skipped.
__global__ __launch_bounds__(256) void k_final(const short* __restrict__ A,
                                               const short* __restrict__ Bt,
                                               const float* __restrict__ bias,
                                               const float* __restrict__ Qres,
                                               const int* __restrict__ idx,
                                               const int* __restrict__ nU,
                                               float* __restrict__ out) {
    __shared__ short lA[2][4096];
    __shared__ short lB[2][2048];
    const int wg = blockIdx.x;                 // 512 blocks
    const int x = wg & 7, r2 = wg >> 3;
    const int tnb = r2 & 15, tmh = r2 >> 4;    // tnb 0..15, tmh 0..3
    const int tmb = x | (tmh << 3);            // 0..31
    const int bb = tmb >> 4;
    const int n = nU[bb];
    if ((tmb & 15) * 128 >= n) return;         // dead (masked) tile
    const int tid = threadIdx.x, w = tid >> 6, ln = tid & 63;
    const int wm = w >> 1, wn = w & 1, r16 = ln & 15, g = ln >> 4;
    const int tn = tnb * 64, tm = tmb * 128;
    const short* Ab = A + (size_t)tm * 1024;
    const short* Bb = Bt + (size_t)tn * 1024;

    f32x4 acc[4][2] = {};
    stage_gswz(Ab, &lA[0][0], tid);
    stage_gswz64(Bb, &lB[0][0], tid);
    int buf = 0;
    for (int ks = 0; ks < 32; ks++) {
        __syncthreads();
        if (ks + 1 < 32) {
            stage_gswz(Ab + (ks + 1) * 32, &lA[buf ^ 1][0], tid);
            stage_gswz64(Bb + (ks + 1) * 32, &lB[buf ^ 1][0], tid);
        }
        frag8 af[4], bg[2];
#pragma unroll
        for (int mf = 0; mf < 4; mf++)
            af[mf] = ldgswz(&lA[buf][0], wm * 64 + mf * 16 + r16, g);
#pragma unroll
        for (int nf = 0; nf < 2; nf++)
            bg[nf] = ldgswz(&lB[buf][0], wn * 32 + nf * 16 + r16, g);
#pragma unroll
        for (int mf = 0; mf < 4; mf++)
#pragma unroll
            for (int nf = 0; nf < 2; nf++)
                acc[mf][nf] = MFMA16(af[mf], bg[nf], acc[mf][nf], 0, 0, 0);
        buf ^= 1;
    }
#pragma unroll
    for (int mf = 0; mf < 4; mf++)
#pragma unroll
        for (int r = 0; r < 4; r++) {
            int m = tm + wm * 64 + mf * 16 + g * 4 + r;
            int i = m & 2047;
            if (i < n) {
                int qg = idx[bb * 2048 + i];
                size_t rowo = ((size_t)(bb * 2048 + qg)) * 1024;
#pragma unroll
                for (int nf = 0; nf < 2; nf++) {
                    int nn = tn + wn * 32 + nf * 16 + r16;
                    float val = acc[mf][nf][r] + bias[nn] + Qres[rowo + nn];
                    out[rowo + nn] = val;
                }
            }
        }
}

// ---------- launch ----------
extern "C" void kernel_launch(void* const* d_in, const int* in_sizes, int n_in,
                              void* d_out, int out_size, void* d_ws, size_t ws_size,
                              hipStream_t stream) {
    (void)in_sizes; (void)n_in; (void)out_size; (void)ws_size;
    const float* Qf  = (const float*)d_in[0];
    const float* Kf  = (const float*)d_in[1];
    const float* Vf  = (const float*)d_in[2];
    const int*   msk = (const int*)d_in[3];
    const float* WQ  = (const float*)d_in[4];
    const float* bQ  = (const float*)d_in[5];
    const float* WK  = (const float*)d_in[6];
    const float* bK  = (const float*)d_in[7];
    const float* WV  = (const float*)d_in[8];
    const float* bV  = (const float*)d_in[9];
    const float* WO  = (const float*)d_in[10];
    const float* bO  = (const float*)d_in[11];
    float* out = (float*)d_out;

    char* p = (char*)d_ws;
    const size_t SZ_ACT = (size_t)4096 * 1024 * 2;  // 8 MB bf16
    const size_t SZ_W   = (size_t)1024 * 1024 * 2;  // 2 MB
    short* Qb  = (short*)p; p += SZ_ACT;
    short* Kb  = (short*)p; p += SZ_ACT;
    short* Vb  = (short*)p; p += SZ_ACT;
    short* q_s = (short*)p; p += SZ_ACT;            // compacted q projections
    short* k_s = (short*)p; p += SZ_ACT;
    short* v_s = (short*)p; p += SZ_ACT;
    short* Wqb = (short*)p; p += SZ_W;
    short* Wkb = (short*)p; p += SZ_W;
    short* Wvb = (short*)p; p += SZ_W;
    short* Wob = (short*)p; p += SZ_W;
    int* idx  = (int*)p; p += (size_t)2 * 2048 * 4;
    int* invp = (int*)p; p += (size_t)2 * 2048 * 4;
    int* nU   = (int*)p; p += 256;
    short* vhatT = Qb;   // dead after proj3
    short* p0    = Kb;   // dead after proj3
    short* p1    = Vb;   // dead after proj3

    // compaction (mask-only dependency)
    k_compact<<<2, 64, 0, stream>>>(msk, idx, invp, nU);

    // fused converts: activations + weights -> bf16 (Q rows permuted; dead rows skipped)
    k_cvt_all<<<4096, 256, 0, stream>>>(Qf, Kf, Vf, WQ, WK, WV, WO, invp, nU,
                                        Qb, Kb, Vb, Wqb, Wkb, Wvb, Wob);

    // fused projections (z: 0=Q scaled+compacted, 1=K, 2=V); XCD tm-swizzle
    k_proj3<<<768, 256, 0, stream>>>(Qb, Kb, Vb, Wqb, Wkb, Wvb,
                                     bQ, bK, bV, nU, q_s, k_s, v_s);

    // column softmax denominators + fused v-scale/transpose (128 k / block)
    k_stats<<<512, 256, 0, stream>>>(k_s, q_s, nU, v_s, vhatT);

    // attention apply, 32 q / wave, split-2 over k, compacted output
    k_apply<<<1024, 256, 0, stream>>>(q_s, k_s, vhatT, nU, p0, p1);

    // sum partials into p0 + fill masked output rows (fused)
    k_psum2m<<<2048, 256, 0, stream>>>(p0, p1, msk, bO, Qf, out);

    // output projection + bias + residual, scatter via idx (dead tiles skipped)
    k_final<<<512, 256, 0, stream>>>(p0, Wob, bO, Qf, idx, nU, out);
}